// Round 6
// baseline (155.680 us; speedup 1.0000x reference)
//
#include <hip/hip_runtime.h>
#include <hip/hip_bf16.h>

#define TOTAL_N   131072
#define NEDGE     4194304
#define NPG       2048
#define IN_DIM_K  128
#define HID_K     256
#define EMB_K     64
#define NAGENT    64

#define F1CAP     4096
#define E1CAP     98304      // 1.5x expected nE1 (~65K)
#define APACK     128        // per-agent e0 slot cap (mean 32, Poisson tail safe)

#define G1        256                 // k_outdeg_e0 blocks (1/CU, full chip)
#define EPB1      (NEDGE / G1)        // 16384 edges per block
#define HWORDS    (TOTAL_N / 8)       // 16384 nibble-packed u32 words

#define SCAN_BLOCKS 2048
#define EPB         2048              // NEDGE / SCAN_BLOCKS
#define E1BUF       256               // per-block hit buffer (mean 32 hits)

// ---------------- workspace layout (bytes), ws_size = 256 MiB ----------------
// zeroed every launch [0, 4784128):
//   0        counters  int[256]         ([1]=nF1 [2]=nE1)
//   1024     inF1      int[F1CAP]       16K
//   17408    e0cnt     int[64]          256B  (= agent in-degree)
//   65536    flag      int[TOTAL_N]     512K
//   589824   agg1      float[F1CAP*HID] 4M
// not zeroed (fully written before read):
//   4784128  loc       int[TOTAL_N]     512K
//   5308416  e0pack    int[64*APACK]    32K
//   5341184  e1src     int[E1CAP]       384K
//   5734400  e1loc     int[E1CAP]       384K
//   6127616  out_deg   u32[TOTAL_N]     512K
//   6651904  wswz      u16[32768]       64K
//   6717440  cursor    int[F1CAP]       16K
//   6733824  bitmap    u64[2048]        16K
//   6750208  partial   u32[G1*HWORDS]   16M
//   23527424 h1        float[F1CAP*HID] 4M
//   27721728 es_pack   int[E1CAP]       384K
// total ~28.1 MB

#define ZERO_SPAN 4784128

typedef float f32x4 __attribute__((ext_vector_type(4)));
typedef short bf16x8 __attribute__((ext_vector_type(8)));

__device__ inline unsigned short f2bf(float f) {   // RNE f32->bf16
    unsigned int u = __float_as_uint(f);
    return (unsigned short)((u + 0x7FFFu + ((u >> 16) & 1u)) >> 16);
}

// K1: out-degree nibble histogram (full chip) + e0 select into per-agent buckets
__global__ __launch_bounds__(1024) void k_outdeg_e0(
    const int* __restrict__ src, const int* __restrict__ dst,
    unsigned int* __restrict__ partial,
    int* __restrict__ flag,
    int* __restrict__ e0pack, int* __restrict__ e0cnt)
{
    __shared__ unsigned int hist[HWORDS];   // 64 KB
    int t = threadIdx.x;
    #pragma unroll
    for (int i = 0; i < HWORDS / 1024; i++) hist[t + i * 1024] = 0u;
    __syncthreads();

    int ebase = blockIdx.x * EPB1;
    const int4* s4 = (const int4*)(src + ebase);
    const int4* d4 = (const int4*)(dst + ebase);
    #pragma unroll
    for (int i = 0; i < EPB1 / 4096; i++) {     // 4 iterations
        int4 sv = s4[i * 1024 + t];
        int4 dv = d4[i * 1024 + t];
        int ss[4] = {sv.x, sv.y, sv.z, sv.w};
        int dd[4] = {dv.x, dv.y, dv.z, dv.w};
        #pragma unroll
        for (int j = 0; j < 4; j++) {
            int s = ss[j], d = dd[j];
            atomicAdd(&hist[s >> 3], 1u << ((s & 7) * 4));
            if ((d & (NPG - 1)) == 0) {
                flag[s] = 1;                     // idempotent race
                int a = d >> 11;
                int slot = atomicAdd(&e0cnt[a], 1);   // 64 hot L2 addrs, ~2K total
                if (slot < APACK) e0pack[a * APACK + slot] = s;
            }
        }
    }
    __syncthreads();
    unsigned int* pout = partial + blockIdx.x * HWORDS;
    #pragma unroll
    for (int i = 0; i < HWORDS / 1024; i++) pout[t + i * 1024] = hist[t + i * 1024];
}

// K2 (fused aux): [0,512) compact+bitmap | [512,576) outdeg reduce | [576,592) wprep
__global__ __launch_bounds__(256) void k_aux(
    const int* __restrict__ flag, int* __restrict__ loc,
    int* __restrict__ counters, unsigned long long* __restrict__ bitmap,
    const unsigned int* __restrict__ partial, unsigned int* __restrict__ out_deg,
    const float* __restrict__ wlin, unsigned short* __restrict__ wswz)
{
    int b = blockIdx.x;
    int t = threadIdx.x;
    if (b < 512) {
        // ---- compact frontier F1 + membership bitmap ----
        __shared__ int cnt, gbase;
        if (t == 0) cnt = 0;
        __syncthreads();
        int v = b * 256 + t;
        int f = flag[v];
        unsigned long long m = __ballot(f != 0);
        if ((t & 63) == 0) bitmap[v >> 6] = m;
        int p = -1;
        if (f) p = atomicAdd(&cnt, 1);
        __syncthreads();
        if (t == 0) gbase = cnt ? atomicAdd(&counters[1], cnt) : 0;
        __syncthreads();
        int l = -1;
        if (p >= 0) {
            int id = gbase + p;
            if (id < F1CAP) l = id;
        }
        loc[v] = l;
    } else if (b < 576) {
        // ---- reduce nibble partials -> u32 out_deg (SWAR u8 lanes) ----
        int w = (b - 512) * 256 + t;            // 16384 words
        unsigned int accE = 0, accO = 0;
        #pragma unroll 8
        for (int g = 0; g < G1; g++) {
            unsigned int v = partial[g * HWORDS + w];
            accE += v & 0x0F0F0F0Fu;
            accO += (v >> 4) & 0x0F0F0F0Fu;
        }
        uint4 lo = make_uint4(accE & 255u, accO & 255u, (accE >> 8) & 255u, (accO >> 8) & 255u);
        uint4 hi = make_uint4((accE >> 16) & 255u, (accO >> 16) & 255u, (accE >> 24) & 255u, (accO >> 24) & 255u);
        ((uint4*)(out_deg + 8 * w))[0] = lo;
        ((uint4*)(out_deg + 8 * w))[1] = hi;
    } else {
        // ---- pre-swizzle wlin into bf16 MFMA B-fragment order ----
        int g = (b - 576) * 256 + t;            // 4096
        int lane = g & 63;
        int ct = (g >> 6) & 15;
        int kt = g >> 10;
        int colbase = ct * 16 + (lane & 15);
        int kbase = kt * 32 + (lane >> 4) * 8;
        unsigned short o[8];
        #pragma unroll
        for (int i = 0; i < 8; i++) o[i] = f2bf(wlin[(kbase + i) * HID_K + colbase]);
        *(ushort4*)(wswz + g * 8)     = make_ushort4(o[0], o[1], o[2], o[3]);
        *(ushort4*)(wswz + g * 8 + 4) = make_ushort4(o[4], o[5], o[6], o[7]);
    }
}

// K3: select edges with dst in F1 — LDS bitmap test, loc gather only on hit
__global__ __launch_bounds__(256) void k_e1_select(
    const int* __restrict__ src, const int* __restrict__ dst,
    const int* __restrict__ loc, const unsigned int* __restrict__ bitmap,
    int* __restrict__ counters,
    int* __restrict__ e1src, int* __restrict__ e1loc,
    int* __restrict__ inF1)
{
    __shared__ unsigned int bm[TOTAL_N / 32];   // 16 KB
    __shared__ int bsrc[E1BUF], bloc[E1BUF];
    __shared__ int cnt, gbase;
    int t = threadIdx.x;
    #pragma unroll
    for (int i = 0; i < 4; i++)
        ((uint4*)bm)[t + i * 256] = ((const uint4*)bitmap)[t + i * 256];
    if (t == 0) cnt = 0;
    __syncthreads();

    int ebase = blockIdx.x * EPB;
    const int4* d4p = (const int4*)(dst + ebase);
    #pragma unroll
    for (int i = 0; i < EPB / 1024; i++) {      // 2 iterations
        int4 d4 = d4p[i * 256 + t];
        int eidx = ebase + (i * 256 + t) * 4;
        int dd[4] = {d4.x, d4.y, d4.z, d4.w};
        #pragma unroll
        for (int j = 0; j < 4; j++) {
            int d = dd[j];
            if ((bm[d >> 5] >> (d & 31)) & 1u) {
                int l = loc[d];
                if (l >= 0) {
                    atomicAdd(&inF1[l], 1);
                    int s = src[eidx + j];
                    int p = atomicAdd(&cnt, 1);
                    if (p < E1BUF) { bsrc[p] = s; bloc[p] = l; }
                    else {
                        int gi = atomicAdd(&counters[2], 1);
                        if (gi < E1CAP) { e1src[gi] = s; e1loc[gi] = l; }
                    }
                }
            }
        }
    }
    __syncthreads();
    int c = min(cnt, E1BUF);
    if (t == 0) gbase = c ? atomicAdd(&counters[2], c) : 0;
    __syncthreads();
    if (t < c) {
        int i = gbase + t;
        if (i < E1CAP) { e1src[i] = bsrc[t]; e1loc[i] = bloc[t]; }
    }
}

// K3b: exclusive scan of inF1 -> cursor (single block)
__global__ __launch_bounds__(1024) void k_scan(
    const int* __restrict__ inF1, const int* __restrict__ counters,
    int* __restrict__ cursor)
{
    __shared__ int a[F1CAP], b[F1CAP];
    int nF1 = min(counters[1], F1CAP);
    int t = threadIdx.x;
    for (int i = t; i < F1CAP; i += 1024) a[i] = (i < nF1) ? inF1[i] : 0;
    __syncthreads();
    int* sp = a; int* dp = b;
    for (int off = 1; off < F1CAP; off <<= 1) {
        for (int i = t; i < F1CAP; i += 1024)
            dp[i] = (i >= off) ? sp[i] + sp[i - off] : sp[i];
        __syncthreads();
        int* tmp = sp; sp = dp; dp = tmp;
    }
    for (int i = t; i < F1CAP; i += 1024)
        cursor[i] = (i == 0) ? 0 : sp[i - 1];
}

// K3c: scatter edges into dst-sorted slots; pack (l<<17)|s
__global__ __launch_bounds__(256) void k_scatter(
    const int* __restrict__ e1src, const int* __restrict__ e1loc,
    const int* __restrict__ counters, int* __restrict__ cursor,
    int* __restrict__ es_pack)
{
    int i = blockIdx.x * 256 + threadIdx.x;
    int nE1 = min(counters[2], E1CAP);
    if (i >= nE1) return;
    int l = e1loc[i];
    int slot = atomicAdd(&cursor[l], 1);
    if (slot < E1CAP) es_pack[slot] = (l << 17) | e1src[i];
}

// K4: MFMA edge-GEMM + fused segmented reduce over sorted dst runs
__global__ __launch_bounds__(256) void k_h0agg(
    const float* __restrict__ x, const unsigned short* __restrict__ wswz,
    const float* __restrict__ blin, const int* __restrict__ es_pack,
    const unsigned int* __restrict__ out_deg, const int* __restrict__ counters,
    float* __restrict__ agg1)
{
    __shared__ unsigned short A[32][136];
    __shared__ float T[32][260];
    __shared__ float escs[32];
    __shared__ int rdst[32];
    __shared__ int rsrc[32];

    int nE1 = min(counters[2], E1CAP);
    int base = blockIdx.x * 32;
    if (base >= nE1) return;
    int t = threadIdx.x;
    int lane = t & 63, wq = t >> 6;

    if (t < 32) {
        int row = base + t;
        int s = -1, d = -1; float e = 0.f;
        if (row < nE1) {
            int p = es_pack[row];
            s = p & 0x1FFFF; d = p >> 17;
            e = rsqrtf((float)max((int)out_deg[s], 1));
        }
        rsrc[t] = s; rdst[t] = d; escs[t] = e;
    }

    bf16x8 bfrag[4][4];
    #pragma unroll
    for (int kt = 0; kt < 4; kt++)
        #pragma unroll
        for (int n = 0; n < 4; n++) {
            int ct = wq * 4 + n;
            bfrag[kt][n] = *(const bf16x8*)(wswz + ((kt * 16 + ct) * 64 + lane) * 8);
        }

    __syncthreads();

    #pragma unroll
    for (int i = 0; i < 4; i++) {
        int idx = t + i * 256;
        int r = idx >> 5;
        int q = idx & 31;
        int s = rsrc[r];
        float4 v = make_float4(0.f, 0.f, 0.f, 0.f);
        if (s >= 0) v = ((const float4*)(x + (long long)s * IN_DIM_K))[q];
        ushort4 h;
        h.x = f2bf(v.x); h.y = f2bf(v.y); h.z = f2bf(v.z); h.w = f2bf(v.w);
        *(ushort4*)&A[r][q * 4] = h;
    }
    __syncthreads();

    f32x4 acc[2][4];
    #pragma unroll
    for (int m = 0; m < 2; m++)
        #pragma unroll
        for (int n = 0; n < 4; n++) acc[m][n] = (f32x4){0.f, 0.f, 0.f, 0.f};

    const unsigned short* Ab = &A[0][0];
    #pragma unroll
    for (int kt = 0; kt < 4; kt++) {
        bf16x8 a0 = *(const bf16x8*)(Ab + ((lane & 15) * 136 + kt * 32 + (lane >> 4) * 8));
        bf16x8 a1 = *(const bf16x8*)(Ab + (((lane & 15) + 16) * 136 + kt * 32 + (lane >> 4) * 8));
        #pragma unroll
        for (int n = 0; n < 4; n++) {
            acc[0][n] = __builtin_amdgcn_mfma_f32_16x16x32_bf16(a0, bfrag[kt][n], acc[0][n], 0, 0, 0);
            acc[1][n] = __builtin_amdgcn_mfma_f32_16x16x32_bf16(a1, bfrag[kt][n], acc[1][n], 0, 0, 0);
        }
    }

    int cbase = lane & 15;
    int rgrp = (lane >> 4) * 4;
    float bj[4];
    #pragma unroll
    for (int n = 0; n < 4; n++) bj[n] = blin[wq * 64 + n * 16 + cbase];
    #pragma unroll
    for (int m = 0; m < 2; m++)
        #pragma unroll
        for (int n = 0; n < 4; n++)
            #pragma unroll
            for (int j = 0; j < 4; j++) {
                int row = m * 16 + rgrp + j;
                int col = wq * 64 + n * 16 + cbase;
                T[row][col] = fmaxf(acc[m][n][j] + bj[n], 0.f) * escs[row];
            }
    __syncthreads();

    float segs = 0.f; int cur = rdst[0];
    #pragma unroll
    for (int r = 0; r < 32; r++) {
        int d = rdst[r];
        if (d != cur) {
            if (cur >= 0) atomicAdd(&agg1[cur * HID_K + t], segs);
            segs = 0.f; cur = d;
        }
        segs += T[r][t];
    }
    if (cur >= 0) atomicAdd(&agg1[cur * HID_K + t], segs);
}

// K5: h1[l] = relu((agg1[l]*in_norm)@w_c0 + b_c0)
__global__ __launch_bounds__(256) void k_h1(
    const float* __restrict__ agg1, const float* __restrict__ wc0,
    const float* __restrict__ bc0,
    const int* __restrict__ inF1,
    const int* __restrict__ counters, float* __restrict__ h1)
{
    __shared__ float as[16][HID_K];
    __shared__ float ns[16];

    int nF1 = min(counters[1], F1CAP);
    int base = blockIdx.x * 16;
    if (base >= nF1) return;
    int t = threadIdx.x;

    if (t < 16) {
        int l = base + t;
        ns[t] = (l < nF1) ? rsqrtf((float)max(inF1[l], 1)) : 0.f;
    }
    __syncthreads();

    #pragma unroll
    for (int i = 0; i < 4; i++) {
        int idx = t + i * 256;
        int e = idx >> 6;
        int q = idx & 63;
        int l = base + e;
        float4 v = make_float4(0.f, 0.f, 0.f, 0.f);
        if (l < nF1) v = ((const float4*)(agg1 + (long long)l * HID_K))[q];
        float sc = ns[e];
        v.x *= sc; v.y *= sc; v.z *= sc; v.w *= sc;
        ((float4*)as[e])[q] = v;
    }
    __syncthreads();

    float acc[16];
    #pragma unroll
    for (int e = 0; e < 16; e++) acc[e] = 0.f;

    int j = t;
    for (int k = 0; k < HID_K; k += 4) {
        float w0 = wc0[(k + 0) * HID_K + j];
        float w1 = wc0[(k + 1) * HID_K + j];
        float w2 = wc0[(k + 2) * HID_K + j];
        float w3 = wc0[(k + 3) * HID_K + j];
        #pragma unroll
        for (int e = 0; e < 16; e++) {
            float4 av = *(const float4*)&as[e][k];
            acc[e] = fmaf(av.x, w0, acc[e]);
            acc[e] = fmaf(av.y, w1, acc[e]);
            acc[e] = fmaf(av.z, w2, acc[e]);
            acc[e] = fmaf(av.w, w3, acc[e]);
        }
    }

    float bj = bc0[j];
    #pragma unroll
    for (int e = 0; e < 16; e++) {
        int l = base + e;
        if (l < nF1) h1[l * HID_K + j] = fmaxf(acc[e] + bj, 0.f);
    }
}

// K6 (fused agg2+final): per agent: gather e0 list, aggregate h1, 2 GEMMs
__global__ __launch_bounds__(256) void k_final(
    const int* __restrict__ e0pack, const int* __restrict__ e0cnt,
    const int* __restrict__ loc, const unsigned int* __restrict__ out_deg,
    const float* __restrict__ h1,
    const float* __restrict__ wc1, const float* __restrict__ bc1,
    const float* __restrict__ wemb, const float* __restrict__ bemb,
    float* __restrict__ out)
{
    __shared__ float a_s[HID_K];
    __shared__ float h2[HID_K];
    __shared__ int   ls[APACK];
    __shared__ float scs[APACK];
    int a = blockIdx.x;
    int t = threadIdx.x;

    int n0 = e0cnt[a];
    int ne = min(n0, APACK);
    if (t < ne) {
        int s = e0pack[a * APACK + t];
        int l = loc[s];
        ls[t] = l;
        scs[t] = (l >= 0) ? rsqrtf((float)max((int)out_deg[s], 1)) : 0.f;
    }
    __syncthreads();

    float acc = 0.f;
    for (int i = 0; i < ne; i++) {
        int l = ls[i];
        if (l >= 0) acc = fmaf(scs[i], h1[l * HID_K + t], acc);
    }
    a_s[t] = acc * rsqrtf((float)max(n0, 1));
    __syncthreads();

    float h = 0.f;
    for (int k = 0; k < HID_K; k++)
        h = fmaf(a_s[k], wc1[k * HID_K + t], h);
    h2[t] = fmaxf(h + bc1[t], 0.f);
    __syncthreads();

    if (t < EMB_K) {
        float o = bemb[t];
        for (int k = 0; k < HID_K; k++)
            o = fmaf(h2[k], wemb[k * EMB_K + t], o);
        out[a * EMB_K + t] = o;
    }
}

extern "C" void kernel_launch(void* const* d_in, const int* in_sizes, int n_in,
                              void* d_out, int out_size, void* d_ws, size_t ws_size,
                              hipStream_t stream)
{
    const float* x    = (const float*)d_in[0];
    const int*   src  = (const int*)d_in[1];
    const int*   dst  = (const int*)d_in[2];
    const float* wlin = (const float*)d_in[5];
    const float* blin = (const float*)d_in[6];
    const float* wc0  = (const float*)d_in[7];
    const float* bc0  = (const float*)d_in[8];
    const float* wc1  = (const float*)d_in[9];
    const float* bc1  = (const float*)d_in[10];
    const float* wemb = (const float*)d_in[11];
    const float* bemb = (const float*)d_in[12];
    float* out = (float*)d_out;

    char* ws = (char*)d_ws;
    int*                counters = (int*)(ws + 0);
    int*                inF1     = (int*)(ws + 1024);
    int*                e0cnt    = (int*)(ws + 17408);
    int*                flag     = (int*)(ws + 65536);
    float*              agg1     = (float*)(ws + 589824);
    int*                loc      = (int*)(ws + 4784128);
    int*                e0pack   = (int*)(ws + 5308416);
    int*                e1src    = (int*)(ws + 5341184);
    int*                e1loc    = (int*)(ws + 5734400);
    unsigned int*       out_deg  = (unsigned int*)(ws + 6127616);
    unsigned short*     wswz     = (unsigned short*)(ws + 6651904);
    int*                cursor   = (int*)(ws + 6717440);
    unsigned long long* bitmap   = (unsigned long long*)(ws + 6733824);
    unsigned int*       partial  = (unsigned int*)(ws + 6750208);
    float*              h1       = (float*)(ws + 23527424);
    int*                es_pack  = (int*)(ws + 27721728);

    hipMemsetAsync(ws, 0, ZERO_SPAN, stream);

    k_outdeg_e0<<<G1, 1024, 0, stream>>>(src, dst, partial, flag, e0pack, e0cnt);
    k_aux<<<592, 256, 0, stream>>>(flag, loc, counters, bitmap,
                                   partial, out_deg, wlin, wswz);
    k_e1_select<<<SCAN_BLOCKS, 256, 0, stream>>>(src, dst, loc,
                                                 (const unsigned int*)bitmap,
                                                 counters, e1src, e1loc, inF1);
    k_scan<<<1, 1024, 0, stream>>>(inF1, counters, cursor);
    k_scatter<<<E1CAP / 256, 256, 0, stream>>>(e1src, e1loc, counters, cursor, es_pack);
    k_h0agg<<<E1CAP / 32, 256, 0, stream>>>(x, wswz, blin, es_pack, out_deg,
                                            counters, agg1);
    k_h1<<<F1CAP / 16, 256, 0, stream>>>(agg1, wc0, bc0, inF1, counters, h1);
    k_final<<<NAGENT, 256, 0, stream>>>(e0pack, e0cnt, loc, out_deg, h1,
                                        wc1, bc1, wemb, bemb, out);
}